// Round 12
// baseline (2456.431 us; speedup 1.0000x reference)
//
#include <hip/hip_runtime.h>
#include <math.h>

typedef unsigned short u16;
typedef unsigned int u32;

#define NB 64
#define NS 256
#define NE 300
#define NH 256
#define NT 22
#define KPAD 304
#define NBS (NB*NS)          // 16384
#define START_TAG 20
#define STOP_TAG 21

// chunk-PAIR split of the 64 f32x4 chunks per gate row; 512 threads = 2 rows/thread:
#define RKC 25               // pairs 0..24 register-resident (200 VGPRs; budget via waves_per_eu(2,2))
#define LDSC 9               // pairs 25..33 LDS-resident (144 KB)
#define SKC 30               // pairs 34..63 streamed from L2 (480 KB/step, coalesced)

typedef float f32x4 __attribute__((ext_vector_type(4)));

__device__ __forceinline__ float fsig(float x) {
    return 1.f / (1.f + expf(-x));
}

// ---------------- pack Wih (pad K) + bias sums ----------------
__global__ __launch_bounds__(64) void pack_wih(const float* __restrict__ Wf, const float* __restrict__ Wb,
                                               const float* __restrict__ bihf, const float* __restrict__ bhhf,
                                               const float* __restrict__ bihb, const float* __restrict__ bhhb,
                                               float* __restrict__ WihP, float* __restrict__ biasP) {
    int j = blockIdx.x & 1023;
    int dir = blockIdx.x >> 10;
    const float* W = dir ? Wb : Wf;
    for (int k = threadIdx.x; k < KPAD; k += 64)
        WihP[((size_t)dir * 1024 + j) * KPAD + k] = (k < NE) ? W[(size_t)j * NE + k] : 0.f;
    if (threadIdx.x == 0) {
        const float* b1 = dir ? bihb : bihf;
        const float* b2 = dir ? bhhb : bhhf;
        biasP[dir * 1024 + j] = b1[j] + b2[j];
    }
}

// ---------------- pack ALL Whh chunk-pairs, coalesced per-wave layout ----------------
// Wpk[((dir*64 + cc)*2 + r)*512 + tid] = Whh[dir][row_r(tid)][4*cc .. +4)
// row_0(tid) = (tid>=256?512:0) + (tid&255); row_1 = row_0 + 256
__global__ __launch_bounds__(256) void pack_wpair(const float* __restrict__ Whf,
                                                  const float* __restrict__ Whb,
                                                  float* __restrict__ Wpk) {
    int idx = blockIdx.x * 256 + threadIdx.x;      // 0 .. 2*64*2*512-1
    int tid = idx & 511;
    int r = (idx >> 9) & 1;
    int cc = (idx >> 10) & 63;
    int dir = idx >> 16;
    const float* W = dir ? Whb : Whf;
    int row = ((tid >= 256) ? 512 : 0) + (tid & 255) + r * 256;
    f32x4 v = *(const f32x4*)(W + (size_t)row * NH + 4 * cc);
    *((f32x4*)Wpk + idx) = v;
}

// ---------------- input-projection GEMM (f32) with fused embedding gather (R7-proven) ----------------
// Xp[dir][bs][n] = (emb[word[bs]]*mask) @ Wih^T + bias. 128x64 tile, 256 threads, 8x4 acc.
__global__ __launch_bounds__(256) void gemm_xproj(const int* __restrict__ word,
                                                  const int* __restrict__ maskp,
                                                  const float* __restrict__ emb,
                                                  const float* __restrict__ WihP,
                                                  const float* __restrict__ biasP,
                                                  float* __restrict__ Xp) {
    int m0 = blockIdx.x * 128;
    int n0 = blockIdx.y * 64;
    int dir = blockIdx.z;
    const float* Bsrc = WihP + (size_t)dir * 1024 * KPAD;
    __shared__ float Asm[16][132];
    __shared__ float Bsm[16][68];
    int tid = threadIdx.x;
    int arow = tid >> 1;          // 0..127
    int acol = (tid & 1) * 8;     // 0 or 8
    int brow = tid >> 2;          // 0..63
    int bcol = (tid & 3) * 4;     // 0,4,8,12
    int ty = tid >> 4;            // 0..15 -> C rows ty*8..+7
    int tx = tid & 15;            // 0..15 -> C cols tx*4..+3
    float acc[8][4] = {};

    int bs = m0 + arow;
    int wi = word[bs];
    int mk = maskp[bs];
    const float* erow = emb + (size_t)wi * NE;

    for (int ks = 0; ks < KPAD / 16; ++ks) {
        int k0 = ks * 16;
        int c0 = k0 + acol;
        f32x4 ga0 = {0.f, 0.f, 0.f, 0.f}, ga1 = {0.f, 0.f, 0.f, 0.f};
        if (mk && c0 < NE)     ga0 = *(const f32x4*)(erow + c0);
        if (mk && c0 + 4 < NE) ga1 = *(const f32x4*)(erow + c0 + 4);
        f32x4 gb = *(const f32x4*)(Bsrc + (size_t)(n0 + brow) * KPAD + k0 + bcol);
        __syncthreads();
#pragma unroll
        for (int j = 0; j < 4; ++j) {
            Asm[acol + j][arow] = ga0[j];
            Asm[acol + 4 + j][arow] = ga1[j];
            Bsm[bcol + j][brow] = gb[j];
        }
        __syncthreads();
#pragma unroll
        for (int k = 0; k < 16; ++k) {
            f32x4 a0 = *(const f32x4*)&Asm[k][ty * 8];
            f32x4 a1 = *(const f32x4*)&Asm[k][ty * 8 + 4];
            f32x4 b4 = *(const f32x4*)&Bsm[k][tx * 4];
#pragma unroll
            for (int i = 0; i < 4; ++i)
#pragma unroll
                for (int j = 0; j < 4; ++j) {
                    acc[i][j] = fmaf(a0[i], b4[j], acc[i][j]);
                    acc[i + 4][j] = fmaf(a1[i], b4[j], acc[i + 4][j]);
                }
        }
    }
    f32x4 bv = *(const f32x4*)(biasP + dir * 1024 + n0 + tx * 4);
#pragma unroll
    for (int i = 0; i < 8; ++i) {
        f32x4 o;
#pragma unroll
        for (int j = 0; j < 4; ++j) o[j] = acc[i][j] + bv[j];
        *(f32x4*)(Xp + ((size_t)dir * NBS + m0 + ty * 8 + i) * 1024 + n0 + tx * 4) = o;
    }
}

// ---------------- recurrent LSTM: block = (dir,b); 512 threads, 2 gate rows each ----------------
// tid<256 -> rows (j, 256+j) = (i,f); tid>=256 -> rows (512+j, 768+j) = (g,o).
// LDS 147KB forces 1 block/CU = 2 waves/SIMD; waves_per_eu(2,2) states that to the
// register allocator so the budget becomes >=256/wave and the 200-reg pin can hold
// (lstm9 evidence: launch_bounds(512,1) granted only 128 -> spill).
__global__ __attribute__((amdgpu_flat_work_group_size(512, 512), amdgpu_waves_per_eu(2, 2)))
void lstm10(const float* __restrict__ Xp,
            const float* __restrict__ Wpk,
            float* __restrict__ hbuf) {
    int bid = blockIdx.x;
    int dir = bid >> 6;
    int b = bid & 63;
    int tid = threadIdx.x;
    int g2 = tid >> 8;
    int j = tid & 255;
    __shared__ f32x4 wlds[2 * LDSC][512];   // 144 KB register-extension (own-lane only)
    __shared__ float h_sh[256];
    __shared__ float2 exch[256];

    const f32x4* wall = (const f32x4*)Wpk + (size_t)dir * 64 * 2 * 512;

    // register-resident pairs 0..RKC-1: coalesced load, whole-vector pinned
    f32x4 wr0[RKC], wr1[RKC];
#pragma unroll
    for (int i = 0; i < RKC; ++i) {
        wr0[i] = wall[(size_t)(i * 2 + 0) * 512 + tid];
        wr1[i] = wall[(size_t)(i * 2 + 1) * 512 + tid];
    }
#pragma unroll
    for (int i = 0; i < RKC; ++i) {
        asm volatile("" : "+v"(wr0[i]));
        asm volatile("" : "+v"(wr1[i]));
    }
    // LDS-resident pairs RKC..RKC+LDSC-1 (own column only)
#pragma unroll
    for (int i = 0; i < LDSC; ++i) {
        wlds[i][tid]        = wall[(size_t)((RKC + i) * 2 + 0) * 512 + tid];
        wlds[LDSC + i][tid] = wall[(size_t)((RKC + i) * 2 + 1) * 512 + tid];
    }

    const f32x4* ws = wall + (size_t)(RKC + LDSC) * 2 * 512;
    int row0 = (g2 ? 512 : 0) + j;
    int row1 = row0 + 256;
    const float* X = Xp + ((size_t)dir * NBS + (size_t)b * NS) * 1024;
    float* Hout = hbuf + ((size_t)dir * NBS + (size_t)b * NS) * NH;
    const f32x4* hs4 = (const f32x4*)h_sh;
    float c = 0.f;
    if (g2 == 0) h_sh[j] = 0.f;
    __syncthreads();

    for (int t = 0; t < NS; ++t) {
        int s = dir ? (NS - 1 - t) : t;
        float acc0 = X[(size_t)s * 1024 + row0];
        float acc1 = X[(size_t)s * 1024 + row1];
        // streamed pairs (coalesced 1KB wave segments)
#pragma unroll 4
        for (int cc = 0; cc < SKC; ++cc) {
            f32x4 wa = ws[(size_t)(cc * 2 + 0) * 512 + tid];
            f32x4 wb = ws[(size_t)(cc * 2 + 1) * 512 + tid];
            f32x4 hq = hs4[RKC + LDSC + cc];
            acc0 = fmaf(wa[0], hq[0], fmaf(wa[1], hq[1], fmaf(wa[2], hq[2], fmaf(wa[3], hq[3], acc0))));
            acc1 = fmaf(wb[0], hq[0], fmaf(wb[1], hq[1], fmaf(wb[2], hq[2], fmaf(wb[3], hq[3], acc1))));
        }
        // register-resident pairs
#pragma unroll
        for (int i = 0; i < RKC; ++i) {
            f32x4 hq = hs4[i];
            acc0 = fmaf(wr0[i][0], hq[0], fmaf(wr0[i][1], hq[1], fmaf(wr0[i][2], hq[2], fmaf(wr0[i][3], hq[3], acc0))));
            acc1 = fmaf(wr1[i][0], hq[0], fmaf(wr1[i][1], hq[1], fmaf(wr1[i][2], hq[2], fmaf(wr1[i][3], hq[3], acc1))));
        }
        // LDS-resident pairs
#pragma unroll
        for (int i = 0; i < LDSC; ++i) {
            f32x4 wa = wlds[i][tid];
            f32x4 wb = wlds[LDSC + i][tid];
            f32x4 hq = hs4[RKC + i];
            acc0 = fmaf(wa[0], hq[0], fmaf(wa[1], hq[1], fmaf(wa[2], hq[2], fmaf(wa[3], hq[3], acc0))));
            acc1 = fmaf(wb[0], hq[0], fmaf(wb[1], hq[1], fmaf(wb[2], hq[2], fmaf(wb[3], hq[3], acc1))));
        }
        // g2=1 owns (g,o): exchange tanh(g), sig(o)
        if (g2) exch[j] = make_float2(tanhf(acc0), fsig(acc1));
        __syncthreads();
        // g2=0 owns (i,f): update c, h; publish
        if (!g2) {
            float gi = fsig(acc0), gf = fsig(acc1);
            float2 go = exch[j];
            c = gf * c + gi * go.x;
            float h = go.y * tanhf(c);
            h_sh[j] = h;
            Hout[(size_t)s * NH + j] = h;
        }
        __syncthreads();
    }
}

// ---------------- heads: feats[bs][22] + token CE partials (wave per 8 positions) ----------------
__global__ __launch_bounds__(256) void feats_kernel(const float* __restrict__ hbuf,
                                                    const float* __restrict__ Wtag, const float* __restrict__ btag,
                                                    const float* __restrict__ Wtok, const float* __restrict__ btok,
                                                    const int* __restrict__ mask, const int* __restrict__ ltok,
                                                    float* __restrict__ feats,
                                                    float* __restrict__ ce_arr, float* __restrict__ cnt_arr) {
    int gw = (blockIdx.x * 256 + threadIdx.x) >> 6;   // 0..2047
    int lane = threadIdx.x & 63;
    float ce = 0.f, cnt = 0.f;
    for (int i = 0; i < 8; ++i) {
        int bs = gw * 8 + i;
        size_t base = (lane < 32) ? ((size_t)bs * NH + lane * 8)
                                  : ((size_t)NBS * NH + (size_t)bs * NH + (lane - 32) * 8);
        f32x4 v0 = *(const f32x4*)(hbuf + base);
        f32x4 v1 = *(const f32x4*)(hbuf + base + 4);
        float vals[8] = {v0[0], v0[1], v0[2], v0[3], v1[0], v1[1], v1[2], v1[3]};
        float t0 = 0.f, t1 = 0.f;
        for (int u = 0; u < 24; ++u) {
            const float* wr = (u < NT) ? (Wtag + (size_t)u * 512) : (Wtok + (size_t)(u - NT) * 512);
            f32x4 w0 = *(const f32x4*)(wr + lane * 8);
            f32x4 w1 = *(const f32x4*)(wr + lane * 8 + 4);
            float d = vals[0] * w0[0] + vals[1] * w0[1] + vals[2] * w0[2] + vals[3] * w0[3]
                    + vals[4] * w1[0] + vals[5] * w1[1] + vals[6] * w1[2] + vals[7] * w1[3];
#pragma unroll
            for (int o = 32; o; o >>= 1) d += __shfl_xor(d, o);
            if (u < NT) {
                if (lane == 0) feats[(size_t)bs * 24 + u] = d + btag[u];
            } else if (u == NT) {
                t0 = d + btok[0];
            } else {
                t1 = d + btok[1];
            }
        }
        if (lane == 0) {
            float m = fmaxf(t0, t1);
            float lse = m + logf(expf(t0 - m) + expf(t1 - m));
            int lab = ltok[bs];
            int mk = mask[bs];
            if (mk == 1 && lab != 0) {
                ce += lse - (lab ? t1 : t0);
                cnt += 1.f;
            }
        }
    }
    if (lane == 0) { ce_arr[gw] = ce; cnt_arr[gw] = cnt; }
}

// ---------------- CRF forward + gold + Viterbi: wave per batch, 4 waves/block ----------------
__global__ __launch_bounds__(256) void crf_kernel(const float* __restrict__ feats,
                                                  const int* __restrict__ mask,
                                                  const int* __restrict__ labels,
                                                  const float* __restrict__ trans,
                                                  float* __restrict__ contrib,
                                                  float* __restrict__ outtags) {
    int wid = threadIdx.x >> 6;           // 0..3 (batch within block)
    int lane = threadIdx.x & 63;
    int b = blockIdx.x * 4 + wid;
    __shared__ float tr[NT * NT];
    __shared__ float ps[4][NT], vs[4][NT];
    __shared__ unsigned char bp[4][NS][NT];
    for (int i = threadIdx.x; i < NT * NT; i += 256) tr[i] = trans[i];
    __syncthreads();                       // the only block-wide barrier

    const float* F = feats + (size_t)b * NS * 24;
    const int* Mrow = mask + b * NS;
    const int* Lrow = labels + b * NS;
    int t = lane;
    float part = 0.f, vit = 0.f;
    if (t < NT) {
        part = F[t] + tr[START_TAG * NT + t];
        vit = part;
        ps[wid][t] = part;
        vs[wid][t] = vit;
    }
    for (int s = 1; s < NS; ++s) {
        int mt = Mrow[s];
        if (t < NT) {
            float ft = F[s * 24 + t];
            float mx = -1e30f, bm = -1e30f;
            int bj = 0;
#pragma unroll
            for (int p = 0; p < NT; ++p) {
                float a = ps[wid][p] + tr[p * NT + t];
                mx = fmaxf(mx, a);
                float v = vs[wid][p] + tr[p * NT + t];
                if (v > bm) { bm = v; bj = p; }   // first-max tie-break (np.argmax)
            }
            float sm = 0.f;
#pragma unroll
            for (int p = 0; p < NT; ++p)
                sm += expf(ps[wid][p] + tr[p * NT + t] - mx);
            float cp = mx + logf(sm) + ft;
            float cv = bm + ft;
            int bi = t;
            if (mt > 0) { part = cp; vit = cv; bi = bj; }
            bp[wid][s][t] = (unsigned char)bi;
            ps[wid][t] = part;     // wave-lockstep: written after all reads this iter
            vs[wid][t] = vit;
        }
    }
    float val = (t < NT) ? part + tr[t * NT + STOP_TAG] : -1e30f;
    float mx = val;
#pragma unroll
    for (int o = 32; o; o >>= 1) mx = fmaxf(mx, __shfl_xor(mx, o));
    float ex = (t < NT) ? expf(val - mx) : 0.f;
#pragma unroll
    for (int o = 32; o; o >>= 1) ex += __shfl_xor(ex, o);
    float fwd = mx + logf(ex);
    if (lane == 0) {
        float bm = -1e30f;
        int bi = 0;
        for (int p = 0; p < NT; ++p) {
            float sc = vs[wid][p] + tr[p * NT + STOP_TAG];
            if (sc > bm) { bm = sc; bi = p; }
        }
        int cur = bi;
        outtags[b * NS + NS - 1] = (float)cur;
        for (int s = NS - 1; s >= 1; --s) {
            cur = bp[wid][s][cur];
            outtags[b * NS + s - 1] = (float)cur;
        }
    }
    float g = 0.f;
    int len = 0;
    for (int s = lane; s < NS; s += 64) {
        int tg = Lrow[s];
        int pv = (s == 0) ? START_TAG : Lrow[s - 1];
        if (Mrow[s] > 0) {
            g += F[s * 24 + tg] + tr[pv * NT + tg];
            len += 1;
        }
    }
#pragma unroll
    for (int o = 32; o; o >>= 1) { g += __shfl_xor(g, o); len += __shfl_xor(len, o); }
    if (lane == 0) {
        int lt = Lrow[len - 1];
        g += tr[lt * NT + STOP_TAG];
        contrib[b] = fwd - g;
    }
}

// ---------------- finalize: deterministic reduction -> d_out[0] ----------------
__global__ __launch_bounds__(256) void finalize_kernel(const float* __restrict__ contrib,
                                                       const float* __restrict__ ce_arr,
                                                       const float* __restrict__ cnt_arr,
                                                       float* __restrict__ out) {
    __shared__ float sA[256], sB[256], sC[256];
    int t = threadIdx.x;
    float a = (t < NB) ? contrib[t] : 0.f;
    float bb = 0.f, cc = 0.f;
    for (int i = t; i < 2048; i += 256) { bb += ce_arr[i]; cc += cnt_arr[i]; }
    sA[t] = a; sB[t] = bb; sC[t] = cc;
    __syncthreads();
    for (int o = 128; o; o >>= 1) {
        if (t < o) { sA[t] += sA[t + o]; sB[t] += sB[t + o]; sC[t] += sC[t + o]; }
        __syncthreads();
    }
    if (t == 0)
        out[0] = sA[0] / (float)NB + sB[0] / fmaxf(sC[0], 1.f);
}

extern "C" void kernel_launch(void* const* d_in, const int* in_sizes, int n_in,
                              void* d_out, int out_size, void* d_ws, size_t ws_size,
                              hipStream_t stream) {
    const int*   word   = (const int*)d_in[0];
    const int*   mask   = (const int*)d_in[1];
    const int*   labels = (const int*)d_in[2];
    const int*   ltok   = (const int*)d_in[3];
    const float* emb    = (const float*)d_in[4];
    const float* Wih_f  = (const float*)d_in[5];
    const float* Whh_f  = (const float*)d_in[6];
    const float* bih_f  = (const float*)d_in[7];
    const float* bhh_f  = (const float*)d_in[8];
    const float* Wih_b  = (const float*)d_in[9];
    const float* Whh_b  = (const float*)d_in[10];
    const float* bih_b  = (const float*)d_in[11];
    const float* bhh_b  = (const float*)d_in[12];
    const float* Wtag   = (const float*)d_in[13];
    const float* btag   = (const float*)d_in[14];
    const float* Wtok   = (const float*)d_in[15];
    const float* btok   = (const float*)d_in[16];
    const float* trans  = (const float*)d_in[17];
    float* out = (float*)d_out;

    char* ws = (char*)d_ws;
    size_t off = 0;
    auto alloc = [&](size_t bytes) { size_t r = off; off += (bytes + 255) & ~(size_t)255; return r; };
    float* WihP   = (float*)(ws + alloc((size_t)2 * 1024 * KPAD * 4));
    float* biasP  = (float*)(ws + alloc((size_t)2 * 1024 * 4));
    float* Wpk    = (float*)(ws + alloc((size_t)2 * 64 * 2 * 512 * 16));
    float* Xp     = (float*)(ws + alloc((size_t)2 * NBS * 1024 * 4));
    float* hbuf   = (float*)(ws + alloc((size_t)2 * NBS * NH * 4));
    float* feats  = (float*)(ws + alloc((size_t)NBS * 24 * 4));
    float* contrib= (float*)(ws + alloc((size_t)NB * 4));
    float* ce_arr = (float*)(ws + alloc((size_t)2048 * 4));
    float* cnt_arr= (float*)(ws + alloc((size_t)2048 * 4));

    pack_wih<<<2048, 64, 0, stream>>>(Wih_f, Wih_b, bih_f, bhh_f, bih_b, bhh_b, WihP, biasP);
    pack_wpair<<<512, 256, 0, stream>>>(Whh_f, Whh_b, Wpk);
    gemm_xproj<<<dim3(NBS / 128, 1024 / 64, 2), 256, 0, stream>>>(word, mask, emb, WihP, biasP, Xp);
    lstm10<<<128, 512, 0, stream>>>(Xp, Wpk, hbuf);
    feats_kernel<<<512, 256, 0, stream>>>(hbuf, Wtag, btag, Wtok, btok, mask, ltok, feats, ce_arr, cnt_arr);
    crf_kernel<<<NB / 4, 256, 0, stream>>>(feats, mask, labels, trans, contrib, out + 1);
    finalize_kernel<<<1, 256, 0, stream>>>(contrib, ce_arr, cnt_arr, out);
}

// Round 13
// 2144.879 us; speedup vs baseline: 1.1453x; 1.1453x over previous
//
#include <hip/hip_runtime.h>
#include <math.h>

typedef unsigned short u16;
typedef unsigned int u32;

#define NB 64
#define NS 256
#define NE 300
#define NH 256
#define NT 22
#define KPAD 304
#define NBS (NB*NS)          // 16384
#define START_TAG 20
#define STOP_TAG 21

// chunk split of the 64 f32x4 chunks per gate row (256 f32), one gate row per thread:
#define RKC 20               // chunks 0..19 compiler-managed (R6/R10 config — measured 1610 us)
#define LDSC 9               // chunks 20..28 LDS-resident (144 KB)
#define SKC 35               // chunks 29..63 streamed from L2 (560 KB/step, coalesced)

typedef float f32x4 __attribute__((ext_vector_type(4)));

__device__ __forceinline__ float fsig(float x) {
    return 1.f / (1.f + expf(-x));
}

// ---------------- pack Wih (pad K) + bias sums ----------------
__global__ __launch_bounds__(64) void pack_wih(const float* __restrict__ Wf, const float* __restrict__ Wb,
                                               const float* __restrict__ bihf, const float* __restrict__ bhhf,
                                               const float* __restrict__ bihb, const float* __restrict__ bhhb,
                                               float* __restrict__ WihP, float* __restrict__ biasP) {
    int j = blockIdx.x & 1023;
    int dir = blockIdx.x >> 10;
    const float* W = dir ? Wb : Wf;
    for (int k = threadIdx.x; k < KPAD; k += 64)
        WihP[((size_t)dir * 1024 + j) * KPAD + k] = (k < NE) ? W[(size_t)j * NE + k] : 0.f;
    if (threadIdx.x == 0) {
        const float* b1 = dir ? bihb : bihf;
        const float* b2 = dir ? bhhb : bhhf;
        biasP[dir * 1024 + j] = b1[j] + b2[j];
    }
}

// ---------------- pack streamed Whh chunks, coalesced per-wave layout (R6/R10) ----------------
// Wst[(dir*SKC + cc)*1024 + row] (f32x4) = Whh[dir][row][4*(RKC+LDSC+cc) .. +4)
__global__ __launch_bounds__(256) void pack_wstream(const float* __restrict__ Whf,
                                                    const float* __restrict__ Whb,
                                                    float* __restrict__ Wst) {
    int idx = blockIdx.x * 256 + threadIdx.x;      // 0 .. 2*SKC*1024-1
    int dir = idx / (SKC * 1024);
    int r = idx % (SKC * 1024);
    int cc = r >> 10;
    int row = r & 1023;
    const float* W = dir ? Whb : Whf;
    f32x4 v = *(const f32x4*)(W + (size_t)row * NH + 4 * (RKC + LDSC + cc));
    *((f32x4*)Wst + idx) = v;
}

// ---------------- input-projection GEMM (f32) with fused embedding gather (R7-proven) ----------------
// Xp[dir][bs][n] = (emb[word[bs]]*mask) @ Wih^T + bias. 128x64 tile, 256 threads, 8x4 acc.
__global__ __launch_bounds__(256) void gemm_xproj(const int* __restrict__ word,
                                                  const int* __restrict__ maskp,
                                                  const float* __restrict__ emb,
                                                  const float* __restrict__ WihP,
                                                  const float* __restrict__ biasP,
                                                  float* __restrict__ Xp) {
    int m0 = blockIdx.x * 128;
    int n0 = blockIdx.y * 64;
    int dir = blockIdx.z;
    const float* Bsrc = WihP + (size_t)dir * 1024 * KPAD;
    __shared__ float Asm[16][132];
    __shared__ float Bsm[16][68];
    int tid = threadIdx.x;
    int arow = tid >> 1;          // 0..127
    int acol = (tid & 1) * 8;     // 0 or 8
    int brow = tid >> 2;          // 0..63
    int bcol = (tid & 3) * 4;     // 0,4,8,12
    int ty = tid >> 4;            // 0..15 -> C rows ty*8..+7
    int tx = tid & 15;            // 0..15 -> C cols tx*4..+3
    float acc[8][4] = {};

    int bs = m0 + arow;
    int wi = word[bs];
    int mk = maskp[bs];
    const float* erow = emb + (size_t)wi * NE;

    for (int ks = 0; ks < KPAD / 16; ++ks) {
        int k0 = ks * 16;
        int c0 = k0 + acol;
        f32x4 ga0 = {0.f, 0.f, 0.f, 0.f}, ga1 = {0.f, 0.f, 0.f, 0.f};
        if (mk && c0 < NE)     ga0 = *(const f32x4*)(erow + c0);
        if (mk && c0 + 4 < NE) ga1 = *(const f32x4*)(erow + c0 + 4);
        f32x4 gb = *(const f32x4*)(Bsrc + (size_t)(n0 + brow) * KPAD + k0 + bcol);
        __syncthreads();
#pragma unroll
        for (int j = 0; j < 4; ++j) {
            Asm[acol + j][arow] = ga0[j];
            Asm[acol + 4 + j][arow] = ga1[j];
            Bsm[bcol + j][brow] = gb[j];
        }
        __syncthreads();
#pragma unroll
        for (int k = 0; k < 16; ++k) {
            f32x4 a0 = *(const f32x4*)&Asm[k][ty * 8];
            f32x4 a1 = *(const f32x4*)&Asm[k][ty * 8 + 4];
            f32x4 b4 = *(const f32x4*)&Bsm[k][tx * 4];
#pragma unroll
            for (int i = 0; i < 4; ++i)
#pragma unroll
                for (int j = 0; j < 4; ++j) {
                    acc[i][j] = fmaf(a0[i], b4[j], acc[i][j]);
                    acc[i + 4][j] = fmaf(a1[i], b4[j], acc[i + 4][j]);
                }
        }
    }
    f32x4 bv = *(const f32x4*)(biasP + dir * 1024 + n0 + tx * 4);
#pragma unroll
    for (int i = 0; i < 8; ++i) {
        f32x4 o;
#pragma unroll
        for (int j = 0; j < 4; ++j) o[j] = acc[i][j] + bv[j];
        *(f32x4*)(Xp + ((size_t)dir * NBS + m0 + ty * 8 + i) * 1024 + n0 + tx * 4) = o;
    }
}

// ---------------- recurrent LSTM (R10-measured lstm5, 1610 us): block = (dir,b); 1024 threads ----------------
__global__ __launch_bounds__(1024, 4) void lstm5(const float* __restrict__ Xp,
                                                 const float* __restrict__ Whf,
                                                 const float* __restrict__ Whb,
                                                 const float* __restrict__ Wst,
                                                 float* __restrict__ hbuf) {
    int bid = blockIdx.x;
    int dir = bid >> 6;
    int b = bid & 63;
    int tid = threadIdx.x;
    int gate = tid >> 8;
    int j = tid & 255;
    __shared__ f32x4 wlds[LDSC][1024];   // 144 KB register-extension (own-lane only)
    __shared__ float h_sh[256];
    __shared__ float exch[3][256];

    const float* W = dir ? Whb : Whf;
    const f32x4* wrow = (const f32x4*)(W + (size_t)tid * NH);
    const f32x4* ws = (const f32x4*)Wst + (size_t)dir * SKC * 1024;

    f32x4 wr[RKC];
#pragma unroll
    for (int i = 0; i < RKC; ++i) wr[i] = wrow[i];
#pragma unroll
    for (int i = 0; i < LDSC; ++i) wlds[i][tid] = wrow[RKC + i];

    const float* X = Xp + ((size_t)dir * NBS + (size_t)b * NS) * 1024;
    float* Hout = hbuf + ((size_t)dir * NBS + (size_t)b * NS) * NH;
    const f32x4* hs4 = (const f32x4*)h_sh;
    float c = 0.f;
    if (gate == 0) h_sh[j] = 0.f;
    __syncthreads();

    for (int t = 0; t < NS; ++t) {
        int s = dir ? (NS - 1 - t) : t;
        float acc = X[(size_t)s * 1024 + tid];
#pragma unroll 5
        for (int cc = 0; cc < SKC; ++cc) {
            f32x4 wv = ws[(size_t)cc * 1024 + tid];
            f32x4 hq = hs4[RKC + LDSC + cc];
            acc = fmaf(wv[0], hq[0], fmaf(wv[1], hq[1], fmaf(wv[2], hq[2], fmaf(wv[3], hq[3], acc))));
        }
#pragma unroll
        for (int i = 0; i < RKC; ++i) {
            f32x4 hq = hs4[i];
            acc = fmaf(wr[i][0], hq[0], fmaf(wr[i][1], hq[1], fmaf(wr[i][2], hq[2], fmaf(wr[i][3], hq[3], acc))));
        }
#pragma unroll
        for (int i = 0; i < LDSC; ++i) {
            f32x4 wv = wlds[i][tid];
            f32x4 hq = hs4[RKC + i];
            acc = fmaf(wv[0], hq[0], fmaf(wv[1], hq[1], fmaf(wv[2], hq[2], fmaf(wv[3], hq[3], acc))));
        }
        if (gate) exch[gate - 1][j] = (gate == 2) ? tanhf(acc) : fsig(acc);
        __syncthreads();
        if (!gate) {
            float gi = fsig(acc);
            float gf = exch[0][j];
            float gg = exch[1][j];
            float oo = exch[2][j];
            c = gf * c + gi * gg;
            float h = oo * tanhf(c);
            h_sh[j] = h;
            Hout[(size_t)s * NH + j] = h;
        }
        __syncthreads();
    }
}

// ---------------- heads: feats[bs][22] + token CE partials (wave per 8 positions) ----------------
__global__ __launch_bounds__(256) void feats_kernel(const float* __restrict__ hbuf,
                                                    const float* __restrict__ Wtag, const float* __restrict__ btag,
                                                    const float* __restrict__ Wtok, const float* __restrict__ btok,
                                                    const int* __restrict__ mask, const int* __restrict__ ltok,
                                                    float* __restrict__ feats,
                                                    float* __restrict__ ce_arr, float* __restrict__ cnt_arr) {
    int gw = (blockIdx.x * 256 + threadIdx.x) >> 6;   // 0..2047
    int lane = threadIdx.x & 63;
    float ce = 0.f, cnt = 0.f;
    for (int i = 0; i < 8; ++i) {
        int bs = gw * 8 + i;
        size_t base = (lane < 32) ? ((size_t)bs * NH + lane * 8)
                                  : ((size_t)NBS * NH + (size_t)bs * NH + (lane - 32) * 8);
        f32x4 v0 = *(const f32x4*)(hbuf + base);
        f32x4 v1 = *(const f32x4*)(hbuf + base + 4);
        float vals[8] = {v0[0], v0[1], v0[2], v0[3], v1[0], v1[1], v1[2], v1[3]};
        float t0 = 0.f, t1 = 0.f;
        for (int u = 0; u < 24; ++u) {
            const float* wr = (u < NT) ? (Wtag + (size_t)u * 512) : (Wtok + (size_t)(u - NT) * 512);
            f32x4 w0 = *(const f32x4*)(wr + lane * 8);
            f32x4 w1 = *(const f32x4*)(wr + lane * 8 + 4);
            float d = vals[0] * w0[0] + vals[1] * w0[1] + vals[2] * w0[2] + vals[3] * w0[3]
                    + vals[4] * w1[0] + vals[5] * w1[1] + vals[6] * w1[2] + vals[7] * w1[3];
#pragma unroll
            for (int o = 32; o; o >>= 1) d += __shfl_xor(d, o);
            if (u < NT) {
                if (lane == 0) feats[(size_t)bs * 24 + u] = d + btag[u];
            } else if (u == NT) {
                t0 = d + btok[0];
            } else {
                t1 = d + btok[1];
            }
        }
        if (lane == 0) {
            float m = fmaxf(t0, t1);
            float lse = m + logf(expf(t0 - m) + expf(t1 - m));
            int lab = ltok[bs];
            int mk = mask[bs];
            if (mk == 1 && lab != 0) {
                ce += lse - (lab ? t1 : t0);
                cnt += 1.f;
            }
        }
    }
    if (lane == 0) { ce_arr[gw] = ce; cnt_arr[gw] = cnt; }
}

// ---------------- CRF forward + gold + Viterbi: wave per batch, 4 waves/block ----------------
__global__ __launch_bounds__(256) void crf_kernel(const float* __restrict__ feats,
                                                  const int* __restrict__ mask,
                                                  const int* __restrict__ labels,
                                                  const float* __restrict__ trans,
                                                  float* __restrict__ contrib,
                                                  float* __restrict__ outtags) {
    int wid = threadIdx.x >> 6;           // 0..3 (batch within block)
    int lane = threadIdx.x & 63;
    int b = blockIdx.x * 4 + wid;
    __shared__ float tr[NT * NT];
    __shared__ float ps[4][NT], vs[4][NT];
    __shared__ unsigned char bp[4][NS][NT];
    for (int i = threadIdx.x; i < NT * NT; i += 256) tr[i] = trans[i];
    __syncthreads();                       // the only block-wide barrier

    const float* F = feats + (size_t)b * NS * 24;
    const int* Mrow = mask + b * NS;
    const int* Lrow = labels + b * NS;
    int t = lane;
    float part = 0.f, vit = 0.f;
    if (t < NT) {
        part = F[t] + tr[START_TAG * NT + t];
        vit = part;
        ps[wid][t] = part;
        vs[wid][t] = vit;
    }
    for (int s = 1; s < NS; ++s) {
        int mt = Mrow[s];
        if (t < NT) {
            float ft = F[s * 24 + t];
            float mx = -1e30f, bm = -1e30f;
            int bj = 0;
#pragma unroll
            for (int p = 0; p < NT; ++p) {
                float a = ps[wid][p] + tr[p * NT + t];
                mx = fmaxf(mx, a);
                float v = vs[wid][p] + tr[p * NT + t];
                if (v > bm) { bm = v; bj = p; }   // first-max tie-break (np.argmax)
            }
            float sm = 0.f;
#pragma unroll
            for (int p = 0; p < NT; ++p)
                sm += expf(ps[wid][p] + tr[p * NT + t] - mx);
            float cp = mx + logf(sm) + ft;
            float cv = bm + ft;
            int bi = t;
            if (mt > 0) { part = cp; vit = cv; bi = bj; }
            bp[wid][s][t] = (unsigned char)bi;
            ps[wid][t] = part;     // wave-lockstep: written after all reads this iter
            vs[wid][t] = vit;
        }
    }
    float val = (t < NT) ? part + tr[t * NT + STOP_TAG] : -1e30f;
    float mx = val;
#pragma unroll
    for (int o = 32; o; o >>= 1) mx = fmaxf(mx, __shfl_xor(mx, o));
    float ex = (t < NT) ? expf(val - mx) : 0.f;
#pragma unroll
    for (int o = 32; o; o >>= 1) ex += __shfl_xor(ex, o);
    float fwd = mx + logf(ex);
    if (lane == 0) {
        float bm = -1e30f;
        int bi = 0;
        for (int p = 0; p < NT; ++p) {
            float sc = vs[wid][p] + tr[p * NT + STOP_TAG];
            if (sc > bm) { bm = sc; bi = p; }
        }
        int cur = bi;
        outtags[b * NS + NS - 1] = (float)cur;
        for (int s = NS - 1; s >= 1; --s) {
            cur = bp[wid][s][cur];
            outtags[b * NS + s - 1] = (float)cur;
        }
    }
    float g = 0.f;
    int len = 0;
    for (int s = lane; s < NS; s += 64) {
        int tg = Lrow[s];
        int pv = (s == 0) ? START_TAG : Lrow[s - 1];
        if (Mrow[s] > 0) {
            g += F[s * 24 + tg] + tr[pv * NT + tg];
            len += 1;
        }
    }
#pragma unroll
    for (int o = 32; o; o >>= 1) { g += __shfl_xor(g, o); len += __shfl_xor(len, o); }
    if (lane == 0) {
        int lt = Lrow[len - 1];
        g += tr[lt * NT + STOP_TAG];
        contrib[b] = fwd - g;
    }
}

// ---------------- finalize: deterministic reduction -> d_out[0] ----------------
__global__ __launch_bounds__(256) void finalize_kernel(const float* __restrict__ contrib,
                                                       const float* __restrict__ ce_arr,
                                                       const float* __restrict__ cnt_arr,
                                                       float* __restrict__ out) {
    __shared__ float sA[256], sB[256], sC[256];
    int t = threadIdx.x;
    float a = (t < NB) ? contrib[t] : 0.f;
    float bb = 0.f, cc = 0.f;
    for (int i = t; i < 2048; i += 256) { bb += ce_arr[i]; cc += cnt_arr[i]; }
    sA[t] = a; sB[t] = bb; sC[t] = cc;
    __syncthreads();
    for (int o = 128; o; o >>= 1) {
        if (t < o) { sA[t] += sA[t + o]; sB[t] += sB[t + o]; sC[t] += sC[t + o]; }
        __syncthreads();
    }
    if (t == 0)
        out[0] = sA[0] / (float)NB + sB[0] / fmaxf(sC[0], 1.f);
}

extern "C" void kernel_launch(void* const* d_in, const int* in_sizes, int n_in,
                              void* d_out, int out_size, void* d_ws, size_t ws_size,
                              hipStream_t stream) {
    const int*   word   = (const int*)d_in[0];
    const int*   mask   = (const int*)d_in[1];
    const int*   labels = (const int*)d_in[2];
    const int*   ltok   = (const int*)d_in[3];
    const float* emb    = (const float*)d_in[4];
    const float* Wih_f  = (const float*)d_in[5];
    const float* Whh_f  = (const float*)d_in[6];
    const float* bih_f  = (const float*)d_in[7];
    const float* bhh_f  = (const float*)d_in[8];
    const float* Wih_b  = (const float*)d_in[9];
    const float* Whh_b  = (const float*)d_in[10];
    const float* bih_b  = (const float*)d_in[11];
    const float* bhh_b  = (const float*)d_in[12];
    const float* Wtag   = (const float*)d_in[13];
    const float* btag   = (const float*)d_in[14];
    const float* Wtok   = (const float*)d_in[15];
    const float* btok   = (const float*)d_in[16];
    const float* trans  = (const float*)d_in[17];
    float* out = (float*)d_out;

    char* ws = (char*)d_ws;
    size_t off = 0;
    auto alloc = [&](size_t bytes) { size_t r = off; off += (bytes + 255) & ~(size_t)255; return r; };
    float* WihP   = (float*)(ws + alloc((size_t)2 * 1024 * KPAD * 4));
    float* biasP  = (float*)(ws + alloc((size_t)2 * 1024 * 4));
    float* Wst    = (float*)(ws + alloc((size_t)2 * SKC * 1024 * 16));
    float* Xp     = (float*)(ws + alloc((size_t)2 * NBS * 1024 * 4));
    float* hbuf   = (float*)(ws + alloc((size_t)2 * NBS * NH * 4));
    float* feats  = (float*)(ws + alloc((size_t)NBS * 24 * 4));
    float* contrib= (float*)(ws + alloc((size_t)NB * 4));
    float* ce_arr = (float*)(ws + alloc((size_t)2048 * 4));
    float* cnt_arr= (float*)(ws + alloc((size_t)2048 * 4));

    pack_wih<<<2048, 64, 0, stream>>>(Wih_f, Wih_b, bih_f, bhh_f, bih_b, bhh_b, WihP, biasP);
    pack_wstream<<<(2 * SKC * 1024) / 256, 256, 0, stream>>>(Whh_f, Whh_b, Wst);
    gemm_xproj<<<dim3(NBS / 128, 1024 / 64, 2), 256, 0, stream>>>(word, mask, emb, WihP, biasP, Xp);
    lstm5<<<128, 1024, 0, stream>>>(Xp, Whh_f, Whh_b, Wst, hbuf);
    feats_kernel<<<512, 256, 0, stream>>>(hbuf, Wtag, btag, Wtok, btok, mask, ltok, feats, ce_arr, cnt_arr);
    crf_kernel<<<NB / 4, 256, 0, stream>>>(feats, mask, labels, trans, contrib, out + 1);
    finalize_kernel<<<1, 256, 0, stream>>>(contrib, ce_arr, cnt_arr, out);
}

// Round 14
// 2143.912 us; speedup vs baseline: 1.1458x; 1.0005x over previous
//
#include <hip/hip_runtime.h>
#include <math.h>

typedef unsigned short u16;
typedef unsigned int u32;

#define NB 64
#define NS 256
#define NE 300
#define NH 256
#define NT 22
#define KPAD 304
#define NBS (NB*NS)          // 16384
#define START_TAG 20
#define STOP_TAG 21

// chunk split of the 64 f32x4 chunks per gate row (256 f32), one gate row per thread:
#define RKC 20               // chunks 0..19 compiler-managed (R6/R10/R13 config — measured 1595-1610 us)
#define LDSC 9               // chunks 20..28 LDS-resident (144 KB)
#define SKC 35               // chunks 29..63 streamed from L2 (560 KB/step, coalesced)

typedef float f32x4 __attribute__((ext_vector_type(4)));

__device__ __forceinline__ float fsig(float x) {
    return 1.f / (1.f + expf(-x));
}

// ---------------- pack Wih (pad K) + bias sums ----------------
__global__ __launch_bounds__(64) void pack_wih(const float* __restrict__ Wf, const float* __restrict__ Wb,
                                               const float* __restrict__ bihf, const float* __restrict__ bhhf,
                                               const float* __restrict__ bihb, const float* __restrict__ bhhb,
                                               float* __restrict__ WihP, float* __restrict__ biasP) {
    int j = blockIdx.x & 1023;
    int dir = blockIdx.x >> 10;
    const float* W = dir ? Wb : Wf;
    for (int k = threadIdx.x; k < KPAD; k += 64)
        WihP[((size_t)dir * 1024 + j) * KPAD + k] = (k < NE) ? W[(size_t)j * NE + k] : 0.f;
    if (threadIdx.x == 0) {
        const float* b1 = dir ? bihb : bihf;
        const float* b2 = dir ? bhhb : bhhf;
        biasP[dir * 1024 + j] = b1[j] + b2[j];
    }
}

// ---------------- pack streamed Whh chunks, coalesced per-wave layout (R6/R10) ----------------
// Wst[(dir*SKC + cc)*1024 + row] (f32x4) = Whh[dir][row][4*(RKC+LDSC+cc) .. +4)
__global__ __launch_bounds__(256) void pack_wstream(const float* __restrict__ Whf,
                                                    const float* __restrict__ Whb,
                                                    float* __restrict__ Wst) {
    int idx = blockIdx.x * 256 + threadIdx.x;      // 0 .. 2*SKC*1024-1
    int dir = idx / (SKC * 1024);
    int r = idx % (SKC * 1024);
    int cc = r >> 10;
    int row = r & 1023;
    const float* W = dir ? Whb : Whf;
    f32x4 v = *(const f32x4*)(W + (size_t)row * NH + 4 * (RKC + LDSC + cc));
    *((f32x4*)Wst + idx) = v;
}

// ---------------- input-projection GEMM (f32), fused gather, DOUBLE-BUFFERED LDS ----------------
// Xp[dir][bs][n] = (emb[word[bs]]*mask) @ Wih^T + bias. 128x64 tile, 256 threads, 8x4 acc.
// One barrier per k-tile; tile k+1 global loads issue before tile k compute (latency hidden).
__global__ __launch_bounds__(256, 4) void gemm_xproj(const int* __restrict__ word,
                                                     const int* __restrict__ maskp,
                                                     const float* __restrict__ emb,
                                                     const float* __restrict__ WihP,
                                                     const float* __restrict__ biasP,
                                                     float* __restrict__ Xp) {
    int m0 = blockIdx.x * 128;
    int n0 = blockIdx.y * 64;
    int dir = blockIdx.z;
    const float* Bsrc = WihP + (size_t)dir * 1024 * KPAD;
    __shared__ float Asm[2][16][132];
    __shared__ float Bsm[2][16][68];
    int tid = threadIdx.x;
    int arow = tid >> 1;          // 0..127
    int acol = (tid & 1) * 8;     // 0 or 8
    int brow = tid >> 2;          // 0..63
    int bcol = (tid & 3) * 4;     // 0,4,8,12
    int ty = tid >> 4;            // 0..15 -> C rows ty*8..+7
    int tx = tid & 15;            // 0..15 -> C cols tx*4..+3
    float acc[8][4] = {};

    int bs = m0 + arow;
    int wi = word[bs];
    int mk = maskp[bs];
    const float* erow = emb + (size_t)wi * NE;

    const int NK = KPAD / 16;     // 19
    f32x4 ga0, ga1, gb;

    auto LOAD = [&](int ks) {
        int c0 = ks * 16 + acol;
        ga0 = f32x4{0.f, 0.f, 0.f, 0.f};
        ga1 = f32x4{0.f, 0.f, 0.f, 0.f};
        if (mk && c0 < NE)     ga0 = *(const f32x4*)(erow + c0);
        if (mk && c0 + 4 < NE) ga1 = *(const f32x4*)(erow + c0 + 4);
        gb = *(const f32x4*)(Bsrc + (size_t)(n0 + brow) * KPAD + ks * 16 + bcol);
    };
    auto WRITE = [&](int buf) {
#pragma unroll
        for (int j = 0; j < 4; ++j) {
            Asm[buf][acol + j][arow] = ga0[j];
            Asm[buf][acol + 4 + j][arow] = ga1[j];
            Bsm[buf][bcol + j][brow] = gb[j];
        }
    };

    LOAD(0);
    WRITE(0);
    __syncthreads();
    for (int ks = 0; ks < NK; ++ks) {
        int cur = ks & 1;
        if (ks + 1 < NK) LOAD(ks + 1);          // loads in flight during compute
#pragma unroll
        for (int k = 0; k < 16; ++k) {
            f32x4 a0 = *(const f32x4*)&Asm[cur][k][ty * 8];
            f32x4 a1 = *(const f32x4*)&Asm[cur][k][ty * 8 + 4];
            f32x4 b4 = *(const f32x4*)&Bsm[cur][k][tx * 4];
#pragma unroll
            for (int i = 0; i < 4; ++i)
#pragma unroll
                for (int j = 0; j < 4; ++j) {
                    acc[i][j] = fmaf(a0[i], b4[j], acc[i][j]);
                    acc[i + 4][j] = fmaf(a1[i], b4[j], acc[i + 4][j]);
                }
        }
        if (ks + 1 < NK) WRITE(cur ^ 1);        // other buffer: prev readers done at last sync
        __syncthreads();
    }
    f32x4 bv = *(const f32x4*)(biasP + dir * 1024 + n0 + tx * 4);
#pragma unroll
    for (int i = 0; i < 8; ++i) {
        f32x4 o;
#pragma unroll
        for (int j = 0; j < 4; ++j) o[j] = acc[i][j] + bv[j];
        *(f32x4*)(Xp + ((size_t)dir * NBS + m0 + ty * 8 + i) * 1024 + n0 + tx * 4) = o;
    }
}

// ---------------- recurrent LSTM (R13-measured lstm5, 1595 us): block = (dir,b); 1024 threads ----------------
__global__ __launch_bounds__(1024, 4) void lstm5(const float* __restrict__ Xp,
                                                 const float* __restrict__ Whf,
                                                 const float* __restrict__ Whb,
                                                 const float* __restrict__ Wst,
                                                 float* __restrict__ hbuf) {
    int bid = blockIdx.x;
    int dir = bid >> 6;
    int b = bid & 63;
    int tid = threadIdx.x;
    int gate = tid >> 8;
    int j = tid & 255;
    __shared__ f32x4 wlds[LDSC][1024];   // 144 KB register-extension (own-lane only)
    __shared__ float h_sh[256];
    __shared__ float exch[3][256];

    const float* W = dir ? Whb : Whf;
    const f32x4* wrow = (const f32x4*)(W + (size_t)tid * NH);
    const f32x4* ws = (const f32x4*)Wst + (size_t)dir * SKC * 1024;

    f32x4 wr[RKC];
#pragma unroll
    for (int i = 0; i < RKC; ++i) wr[i] = wrow[i];
#pragma unroll
    for (int i = 0; i < LDSC; ++i) wlds[i][tid] = wrow[RKC + i];

    const float* X = Xp + ((size_t)dir * NBS + (size_t)b * NS) * 1024;
    float* Hout = hbuf + ((size_t)dir * NBS + (size_t)b * NS) * NH;
    const f32x4* hs4 = (const f32x4*)h_sh;
    float c = 0.f;
    if (gate == 0) h_sh[j] = 0.f;
    __syncthreads();

    for (int t = 0; t < NS; ++t) {
        int s = dir ? (NS - 1 - t) : t;
        float acc = X[(size_t)s * 1024 + tid];
#pragma unroll 5
        for (int cc = 0; cc < SKC; ++cc) {
            f32x4 wv = ws[(size_t)cc * 1024 + tid];
            f32x4 hq = hs4[RKC + LDSC + cc];
            acc = fmaf(wv[0], hq[0], fmaf(wv[1], hq[1], fmaf(wv[2], hq[2], fmaf(wv[3], hq[3], acc))));
        }
#pragma unroll
        for (int i = 0; i < RKC; ++i) {
            f32x4 hq = hs4[i];
            acc = fmaf(wr[i][0], hq[0], fmaf(wr[i][1], hq[1], fmaf(wr[i][2], hq[2], fmaf(wr[i][3], hq[3], acc))));
        }
#pragma unroll
        for (int i = 0; i < LDSC; ++i) {
            f32x4 wv = wlds[i][tid];
            f32x4 hq = hs4[RKC + i];
            acc = fmaf(wv[0], hq[0], fmaf(wv[1], hq[1], fmaf(wv[2], hq[2], fmaf(wv[3], hq[3], acc))));
        }
        if (gate) exch[gate - 1][j] = (gate == 2) ? tanhf(acc) : fsig(acc);
        __syncthreads();
        if (!gate) {
            float gi = fsig(acc);
            float gf = exch[0][j];
            float gg = exch[1][j];
            float oo = exch[2][j];
            c = gf * c + gi * gg;
            float h = oo * tanhf(c);
            h_sh[j] = h;
            Hout[(size_t)s * NH + j] = h;
        }
        __syncthreads();
    }
}

// ---------------- heads: feats[bs][22] + token CE partials (wave per 8 positions) ----------------
__global__ __launch_bounds__(256) void feats_kernel(const float* __restrict__ hbuf,
                                                    const float* __restrict__ Wtag, const float* __restrict__ btag,
                                                    const float* __restrict__ Wtok, const float* __restrict__ btok,
                                                    const int* __restrict__ mask, const int* __restrict__ ltok,
                                                    float* __restrict__ feats,
                                                    float* __restrict__ ce_arr, float* __restrict__ cnt_arr) {
    int gw = (blockIdx.x * 256 + threadIdx.x) >> 6;   // 0..2047
    int lane = threadIdx.x & 63;
    float ce = 0.f, cnt = 0.f;
    for (int i = 0; i < 8; ++i) {
        int bs = gw * 8 + i;
        size_t base = (lane < 32) ? ((size_t)bs * NH + lane * 8)
                                  : ((size_t)NBS * NH + (size_t)bs * NH + (lane - 32) * 8);
        f32x4 v0 = *(const f32x4*)(hbuf + base);
        f32x4 v1 = *(const f32x4*)(hbuf + base + 4);
        float vals[8] = {v0[0], v0[1], v0[2], v0[3], v1[0], v1[1], v1[2], v1[3]};
        float t0 = 0.f, t1 = 0.f;
        for (int u = 0; u < 24; ++u) {
            const float* wr = (u < NT) ? (Wtag + (size_t)u * 512) : (Wtok + (size_t)(u - NT) * 512);
            f32x4 w0 = *(const f32x4*)(wr + lane * 8);
            f32x4 w1 = *(const f32x4*)(wr + lane * 8 + 4);
            float d = vals[0] * w0[0] + vals[1] * w0[1] + vals[2] * w0[2] + vals[3] * w0[3]
                    + vals[4] * w1[0] + vals[5] * w1[1] + vals[6] * w1[2] + vals[7] * w1[3];
#pragma unroll
            for (int o = 32; o; o >>= 1) d += __shfl_xor(d, o);
            if (u < NT) {
                if (lane == 0) feats[(size_t)bs * 24 + u] = d + btag[u];
            } else if (u == NT) {
                t0 = d + btok[0];
            } else {
                t1 = d + btok[1];
            }
        }
        if (lane == 0) {
            float m = fmaxf(t0, t1);
            float lse = m + logf(expf(t0 - m) + expf(t1 - m));
            int lab = ltok[bs];
            int mk = mask[bs];
            if (mk == 1 && lab != 0) {
                ce += lse - (lab ? t1 : t0);
                cnt += 1.f;
            }
        }
    }
    if (lane == 0) { ce_arr[gw] = ce; cnt_arr[gw] = cnt; }
}

// ---------------- CRF forward + gold + Viterbi: wave per batch, 4 waves/block ----------------
__global__ __launch_bounds__(256) void crf_kernel(const float* __restrict__ feats,
                                                  const int* __restrict__ mask,
                                                  const int* __restrict__ labels,
                                                  const float* __restrict__ trans,
                                                  float* __restrict__ contrib,
                                                  float* __restrict__ outtags) {
    int wid = threadIdx.x >> 6;           // 0..3 (batch within block)
    int lane = threadIdx.x & 63;
    int b = blockIdx.x * 4 + wid;
    __shared__ float tr[NT * NT];
    __shared__ float ps[4][NT], vs[4][NT];
    __shared__ unsigned char bp[4][NS][NT];
    for (int i = threadIdx.x; i < NT * NT; i += 256) tr[i] = trans[i];
    __syncthreads();                       // the only block-wide barrier

    const float* F = feats + (size_t)b * NS * 24;
    const int* Mrow = mask + b * NS;
    const int* Lrow = labels + b * NS;
    int t = lane;
    float part = 0.f, vit = 0.f;
    if (t < NT) {
        part = F[t] + tr[START_TAG * NT + t];
        vit = part;
        ps[wid][t] = part;
        vs[wid][t] = vit;
    }
    for (int s = 1; s < NS; ++s) {
        int mt = Mrow[s];
        if (t < NT) {
            float ft = F[s * 24 + t];
            float mx = -1e30f, bm = -1e30f;
            int bj = 0;
#pragma unroll
            for (int p = 0; p < NT; ++p) {
                float a = ps[wid][p] + tr[p * NT + t];
                mx = fmaxf(mx, a);
                float v = vs[wid][p] + tr[p * NT + t];
                if (v > bm) { bm = v; bj = p; }   // first-max tie-break (np.argmax)
            }
            float sm = 0.f;
#pragma unroll
            for (int p = 0; p < NT; ++p)
                sm += expf(ps[wid][p] + tr[p * NT + t] - mx);
            float cp = mx + logf(sm) + ft;
            float cv = bm + ft;
            int bi = t;
            if (mt > 0) { part = cp; vit = cv; bi = bj; }
            bp[wid][s][t] = (unsigned char)bi;
            ps[wid][t] = part;     // wave-lockstep: written after all reads this iter
            vs[wid][t] = vit;
        }
    }
    float val = (t < NT) ? part + tr[t * NT + STOP_TAG] : -1e30f;
    float mx = val;
#pragma unroll
    for (int o = 32; o; o >>= 1) mx = fmaxf(mx, __shfl_xor(mx, o));
    float ex = (t < NT) ? expf(val - mx) : 0.f;
#pragma unroll
    for (int o = 32; o; o >>= 1) ex += __shfl_xor(ex, o);
    float fwd = mx + logf(ex);
    if (lane == 0) {
        float bm = -1e30f;
        int bi = 0;
        for (int p = 0; p < NT; ++p) {
            float sc = vs[wid][p] + tr[p * NT + STOP_TAG];
            if (sc > bm) { bm = sc; bi = p; }
        }
        int cur = bi;
        outtags[b * NS + NS - 1] = (float)cur;
        for (int s = NS - 1; s >= 1; --s) {
            cur = bp[wid][s][cur];
            outtags[b * NS + s - 1] = (float)cur;
        }
    }
    float g = 0.f;
    int len = 0;
    for (int s = lane; s < NS; s += 64) {
        int tg = Lrow[s];
        int pv = (s == 0) ? START_TAG : Lrow[s - 1];
        if (Mrow[s] > 0) {
            g += F[s * 24 + tg] + tr[pv * NT + tg];
            len += 1;
        }
    }
#pragma unroll
    for (int o = 32; o; o >>= 1) { g += __shfl_xor(g, o); len += __shfl_xor(len, o); }
    if (lane == 0) {
        int lt = Lrow[len - 1];
        g += tr[lt * NT + STOP_TAG];
        contrib[b] = fwd - g;
    }
}

// ---------------- finalize: deterministic reduction -> d_out[0] ----------------
__global__ __launch_bounds__(256) void finalize_kernel(const float* __restrict__ contrib,
                                                       const float* __restrict__ ce_arr,
                                                       const float* __restrict__ cnt_arr,
                                                       float* __restrict__ out) {
    __shared__ float sA[256], sB[256], sC[256];
    int t = threadIdx.x;
    float a = (t < NB) ? contrib[t] : 0.f;
    float bb = 0.f, cc = 0.f;
    for (int i = t; i < 2048; i += 256) { bb += ce_arr[i]; cc += cnt_arr[i]; }
    sA[t] = a; sB[t] = bb; sC[t] = cc;
    __syncthreads();
    for (int o = 128; o; o >>= 1) {
        if (t < o) { sA[t] += sA[t + o]; sB[t] += sB[t + o]; sC[t] += sC[t + o]; }
        __syncthreads();
    }
    if (t == 0)
        out[0] = sA[0] / (float)NB + sB[0] / fmaxf(sC[0], 1.f);
}

extern "C" void kernel_launch(void* const* d_in, const int* in_sizes, int n_in,
                              void* d_out, int out_size, void* d_ws, size_t ws_size,
                              hipStream_t stream) {
    const int*   word   = (const int*)d_in[0];
    const int*   mask   = (const int*)d_in[1];
    const int*   labels = (const int*)d_in[2];
    const int*   ltok   = (const int*)d_in[3];
    const float* emb    = (const float*)d_in[4];
    const float* Wih_f  = (const float*)d_in[5];
    const float* Whh_f  = (const float*)d_in[6];
    const float* bih_f  = (const float*)d_in[7];
    const float* bhh_f  = (const float*)d_in[8];
    const float* Wih_b  = (const float*)d_in[9];
    const float* Whh_b  = (const float*)d_in[10];
    const float* bih_b  = (const float*)d_in[11];
    const float* bhh_b  = (const float*)d_in[12];
    const float* Wtag   = (const float*)d_in[13];
    const float* btag   = (const float*)d_in[14];
    const float* Wtok   = (const float*)d_in[15];
    const float* btok   = (const float*)d_in[16];
    const float* trans  = (const float*)d_in[17];
    float* out = (float*)d_out;

    char* ws = (char*)d_ws;
    size_t off = 0;
    auto alloc = [&](size_t bytes) { size_t r = off; off += (bytes + 255) & ~(size_t)255; return r; };
    float* WihP   = (float*)(ws + alloc((size_t)2 * 1024 * KPAD * 4));
    float* biasP  = (float*)(ws + alloc((size_t)2 * 1024 * 4));
    float* Wst    = (float*)(ws + alloc((size_t)2 * SKC * 1024 * 16));
    float* Xp     = (float*)(ws + alloc((size_t)2 * NBS * 1024 * 4));
    float* hbuf   = (float*)(ws + alloc((size_t)2 * NBS * NH * 4));
    float* feats  = (float*)(ws + alloc((size_t)NBS * 24 * 4));
    float* contrib= (float*)(ws + alloc((size_t)NB * 4));
    float* ce_arr = (float*)(ws + alloc((size_t)2048 * 4));
    float* cnt_arr= (float*)(ws + alloc((size_t)2048 * 4));

    pack_wih<<<2048, 64, 0, stream>>>(Wih_f, Wih_b, bih_f, bhh_f, bih_b, bhh_b, WihP, biasP);
    pack_wstream<<<(2 * SKC * 1024) / 256, 256, 0, stream>>>(Whh_f, Whh_b, Wst);
    gemm_xproj<<<dim3(NBS / 128, 1024 / 64, 2), 256, 0, stream>>>(word, mask, emb, WihP, biasP, Xp);
    lstm5<<<128, 1024, 0, stream>>>(Xp, Whh_f, Whh_b, Wst, hbuf);
    feats_kernel<<<512, 256, 0, stream>>>(hbuf, Wtag, btag, Wtok, btok, mask, ltok, feats, ce_arr, cnt_arr);
    crf_kernel<<<NB / 4, 256, 0, stream>>>(feats, mask, labels, trans, contrib, out + 1);
    finalize_kernel<<<1, 256, 0, stream>>>(contrib, ce_arr, cnt_arr, out);
}